// Round 12
// baseline (310.948 us; speedup 1.0000x reference)
//
#include <hip/hip_runtime.h>
#include <hip/hip_bf16.h>
#include <math.h>

// Problem constants
constexpr int Bc = 8;
constexpr int Sc = 1024;
constexpr int Dc = 768;
constexpr int Hc = 12;
constexpr int DKc = 64;
constexpr int BSc = Bc * Sc;          // 8192 rows
constexpr size_t HEAD_ELEMS = (size_t)Bc * Hc * Sc * DKc;  // 6291456
constexpr size_t OUT_ELEMS  = (size_t)Bc * Sc * Dc;        // 6291456

typedef __attribute__((ext_vector_type(8))) short short8;
typedef __attribute__((ext_vector_type(4))) short short4v;
typedef __attribute__((ext_vector_type(4))) float f32x4;

__device__ __forceinline__ short f2bf(float x) {
  __hip_bfloat16 h = __float2bfloat16(x);
  short r;
  __builtin_memcpy(&r, &h, 2);
  return r;
}

// async global->LDS, 16B per lane. LDS dest = wave-uniform base + lane*16.
__device__ __forceinline__ void gload16(const void* g, void* l) {
  __builtin_amdgcn_global_load_lds(
      (const __attribute__((address_space(1))) void*)g,
      (__attribute__((address_space(3))) void*)l, 16, 0, 0);
}

// ---------------------------------------------------------------------------
// Input cast: fp32 -> bf16, one short8 per thread.  Grid (3072, 3).
// ---------------------------------------------------------------------------
__global__ __launch_bounds__(256) void cast3(
    const float* __restrict__ q, const float* __restrict__ k,
    const float* __restrict__ v, __hip_bfloat16* __restrict__ dq,
    __hip_bfloat16* __restrict__ dk, __hip_bfloat16* __restrict__ dv) {
  const int which = blockIdx.y;
  const float* src = (which == 0) ? q : (which == 1) ? k : v;
  __hip_bfloat16* dst = (which == 0) ? dq : (which == 1) ? dk : dv;
  const size_t i = ((size_t)blockIdx.x * 256 + threadIdx.x) * 8;
  const float4 f0 = *reinterpret_cast<const float4*>(src + i);
  const float4 f1 = *reinterpret_cast<const float4*>(src + i + 4);
  short8 s;
  s[0] = f2bf(f0.x); s[1] = f2bf(f0.y); s[2] = f2bf(f0.z); s[3] = f2bf(f0.w);
  s[4] = f2bf(f1.x); s[5] = f2bf(f1.y); s[6] = f2bf(f1.z); s[7] = f2bf(f1.w);
  *reinterpret_cast<short8*>(dst + i) = s;
}

// ---------------------------------------------------------------------------
// Fused weight transpose+cast: Wt[z][n][k] bf16 = W_z[k][n] fp32.
// Grid (24,24,4), 256 threads.
// ---------------------------------------------------------------------------
__global__ __launch_bounds__(256) void wtrans4(
    const float* __restrict__ W0, const float* __restrict__ W1,
    const float* __restrict__ W2, const float* __restrict__ W3,
    __hip_bfloat16* __restrict__ Wt0) {
  __shared__ float t[32][33];
  const int z = blockIdx.z;
  const float* W = (z == 0) ? W0 : (z == 1) ? W1 : (z == 2) ? W2 : W3;
  __hip_bfloat16* Wt = Wt0 + (size_t)z * Dc * Dc;
  const int tx = threadIdx.x & 31, ty = threadIdx.x >> 5;
  const int bx = blockIdx.x * 32;   // n-base
  const int by = blockIdx.y * 32;   // k-base
  #pragma unroll
  for (int i = 0; i < 32; i += 8)
    t[ty + i][tx] = W[(size_t)(by + ty + i) * Dc + bx + tx];
  __syncthreads();
  #pragma unroll
  for (int i = 0; i < 32; i += 8)
    Wt[(size_t)(bx + ty + i) * Dc + by + tx] = __float2bfloat16(t[tx][ty + i]);
}

// ---------------------------------------------------------------------------
// Pipelined 2-phase BF16 GEMM core (128x128 tile, BK=32) -- verified r11.
// ---------------------------------------------------------------------------
__device__ __forceinline__ void stage_tiles(
    const __hip_bfloat16* A, const __hip_bfloat16* Wt, int row0, int col0,
    int k0, int wv, int lane, __hip_bfloat16* bufA, __hip_bfloat16* bufB) {
  #pragma unroll
  for (int j = 0; j < 2; j++) {
    const int rr = j * 64 + wv * 16;
    const int r = rr + (lane >> 2);
    const int kc = k0 + (lane & 3) * 8;
    gload16(A + (size_t)(row0 + r) * Dc + kc, bufA + rr * 32);
    gload16(Wt + (size_t)(col0 + r) * Dc + kc, bufB + rr * 32);
  }
}

__device__ __forceinline__ void compute_tiles(
    const __hip_bfloat16* bufA, const __hip_bfloat16* bufB, int wr, int wc,
    int l15, int g, f32x4 (&acc)[4][4]) {
  short8 a[4], b[4];
  #pragma unroll
  for (int ai = 0; ai < 4; ai++)
    a[ai] = *reinterpret_cast<const short8*>(
        &bufA[(wr * 64 + ai * 16 + l15) * 32 + g * 8]);
  #pragma unroll
  for (int bj = 0; bj < 4; bj++)
    b[bj] = *reinterpret_cast<const short8*>(
        &bufB[(wc * 64 + bj * 16 + l15) * 32 + g * 8]);
  #pragma unroll
  for (int ai = 0; ai < 4; ai++)
    #pragma unroll
    for (int bj = 0; bj < 4; bj++)
      acc[ai][bj] = __builtin_amdgcn_mfma_f32_16x16x32_bf16(
          a[ai], b[bj], acc[ai][bj], 0, 0, 0);
}

#define GEMM_PIPELINE(A_, Wt_)                                          \
  stage_tiles(A_, Wt_, row0, col0, 0, wv, lane, As0, Bs0);              \
  __syncthreads();                                                      \
  for (int t = 0; t < 24; t += 2) {                                     \
    stage_tiles(A_, Wt_, row0, col0, (t + 1) * 32, wv, lane, As1, Bs1); \
    compute_tiles(As0, Bs0, wr, wc, l15, g, acc);                       \
    __syncthreads();                                                    \
    if (t + 2 < 24)                                                     \
      stage_tiles(A_, Wt_, row0, col0, (t + 2) * 32, wv, lane, As0, Bs0);\
    compute_tiles(As1, Bs1, wr, wc, l15, g, acc);                       \
    __syncthreads();                                                    \
  }

// ---------------------------------------------------------------------------
// Fused QKV GEMM (verified r11).  Grid (384, 3).
// ---------------------------------------------------------------------------
__global__ __launch_bounds__(256) void gemm_qkv(
    const __hip_bfloat16* __restrict__ Aq, const __hip_bfloat16* __restrict__ Ak,
    const __hip_bfloat16* __restrict__ Av, const __hip_bfloat16* __restrict__ Wt0,
    const float* __restrict__ bq, const float* __restrict__ bk,
    const float* __restrict__ bv, __hip_bfloat16* __restrict__ out0) {
  __shared__ __hip_bfloat16 As0[128 * 32], Bs0[128 * 32];
  __shared__ __hip_bfloat16 As1[128 * 32], Bs1[128 * 32];

  const int tid = threadIdx.x;
  const int lane = tid & 63;
  const int wv = tid >> 6;
  const int l15 = lane & 15;
  const int g = lane >> 4;
  const int wr = wv >> 1, wc = wv & 1;

  const int proj = blockIdx.y;
  const __hip_bfloat16* A = (proj == 0) ? Aq : (proj == 1) ? Ak : Av;
  const float* bias = (proj == 0) ? bq : (proj == 1) ? bk : bv;
  const __hip_bfloat16* Wt = Wt0 + (size_t)proj * Dc * Dc;
  __hip_bfloat16* out = out0 + (size_t)proj * HEAD_ELEMS;

  const int orig = blockIdx.x;
  const int swz = (orig & 7) * 48 + (orig >> 3);
  const int row0 = (swz / (Dc / 128)) * 128;
  const int col0 = (swz % (Dc / 128)) * 128;

  f32x4 acc[4][4];
  #pragma unroll
  for (int ai = 0; ai < 4; ai++)
    #pragma unroll
    for (int bj = 0; bj < 4; bj++) acc[ai][bj] = f32x4{0.f, 0.f, 0.f, 0.f};

  GEMM_PIPELINE(A, Wt)

  const int mb = row0 + wr * 64, nb = col0 + wc * 64;
  if (proj < 2) {
    #pragma unroll
    for (int ai = 0; ai < 4; ai++)
      #pragma unroll
      for (int bj = 0; bj < 4; bj++) {
        const int n = nb + bj * 16 + l15;
        const int h_ = n >> 6, dk = n & 63;
        const float bn = bias[n];
        #pragma unroll
        for (int reg = 0; reg < 4; reg++) {
          const int m = mb + ai * 16 + g * 4 + reg;
          const int b_ = m >> 10, s_ = m & 1023;
          out[(((size_t)(b_ * Hc + h_)) * Sc + s_) * DKc + dk] =
              __float2bfloat16(acc[ai][bj][reg] + bn);
        }
      }
  } else {
    #pragma unroll
    for (int ai = 0; ai < 4; ai++)
      #pragma unroll
      for (int bj = 0; bj < 4; bj++) {
        const int n = nb + bj * 16 + l15;          // d index
        const int h_ = n >> 6, dk = n & 63;
        const float bn = bias[n];
        const int m0 = mb + ai * 16 + g * 4;       // s base (mult of 4)
        const int b_ = m0 >> 10, s0 = m0 & 1023;
        short4v sv;
        sv[0] = f2bf(acc[ai][bj][0] + bn);
        sv[1] = f2bf(acc[ai][bj][1] + bn);
        sv[2] = f2bf(acc[ai][bj][2] + bn);
        sv[3] = f2bf(acc[ai][bj][3] + bn);
        *reinterpret_cast<short4v*>(
            &out[(((size_t)(b_ * Hc + h_)) * DKc + dk) * Sc + s0]) = sv;
      }
  }
}

// ---------------------------------------------------------------------------
// Output projection, 64x128 tiles -> 768 blocks (2x TLP of 128x128).
// hidden[8192,768] fp32 = ctx_bf @ WtD^T + bd.  4 waves 2x2: 32x64/wave.
// ---------------------------------------------------------------------------
__global__ __launch_bounds__(256) void gemm_o64(
    const __hip_bfloat16* __restrict__ A, const __hip_bfloat16* __restrict__ Wt,
    const float* __restrict__ bias, float* __restrict__ out) {
  __shared__ __hip_bfloat16 As0[64 * 32], As1[64 * 32];    // 4 KB each
  __shared__ __hip_bfloat16 Bs0[128 * 32], Bs1[128 * 32];  // 8 KB each

  const int tid = threadIdx.x;
  const int lane = tid & 63;
  const int wv = tid >> 6;
  const int l15 = lane & 15;
  const int g = lane >> 4;
  const int wr = wv >> 1, wc = wv & 1;

  // XCD swizzle; nwg = 768, divisible by 8 -> bijective
  const int orig = blockIdx.x;
  const int swz = (orig & 7) * 96 + (orig >> 3);
  const int row0 = (swz / (Dc / 128)) * 64;
  const int col0 = (swz % (Dc / 128)) * 128;

  f32x4 acc[2][4];
  #pragma unroll
  for (int ai = 0; ai < 2; ai++)
    #pragma unroll
    for (int bj = 0; bj < 4; bj++) acc[ai][bj] = f32x4{0.f, 0.f, 0.f, 0.f};

  auto STAGE = [&](int k0, __hip_bfloat16* bufA, __hip_bfloat16* bufB) {
    const int r = wv * 16 + (lane >> 2);
    const int kc = k0 + (lane & 3) * 8;
    gload16(A + (size_t)(row0 + r) * Dc + kc, bufA + (wv * 16) * 32);
    #pragma unroll
    for (int j = 0; j < 2; j++) {
      const int rr = j * 64 + wv * 16;
      const int rn = rr + (lane >> 2);
      gload16(Wt + (size_t)(col0 + rn) * Dc + kc, bufB + rr * 32);
    }
  };
  auto COMP = [&](const __hip_bfloat16* bufA, const __hip_bfloat16* bufB) {
    short8 a[2], b[4];
    #pragma unroll
    for (int ai = 0; ai < 2; ai++)
      a[ai] = *reinterpret_cast<const short8*>(
          &bufA[(wr * 32 + ai * 16 + l15) * 32 + g * 8]);
    #pragma unroll
    for (int bj = 0; bj < 4; bj++)
      b[bj] = *reinterpret_cast<const short8*>(
          &bufB[(wc * 64 + bj * 16 + l15) * 32 + g * 8]);
    #pragma unroll
    for (int ai = 0; ai < 2; ai++)
      #pragma unroll
      for (int bj = 0; bj < 4; bj++)
        acc[ai][bj] = __builtin_amdgcn_mfma_f32_16x16x32_bf16(
            a[ai], b[bj], acc[ai][bj], 0, 0, 0);
  };

  STAGE(0, As0, Bs0);
  __syncthreads();
  for (int t = 0; t < 24; t += 2) {
    STAGE((t + 1) * 32, As1, Bs1);
    COMP(As0, Bs0);
    __syncthreads();
    if (t + 2 < 24) STAGE((t + 2) * 32, As0, Bs0);
    COMP(As1, Bs1);
    __syncthreads();
  }

  const int mb = row0 + wr * 32, nb = col0 + wc * 64;
  #pragma unroll
  for (int ai = 0; ai < 2; ai++)
    #pragma unroll
    for (int bj = 0; bj < 4; bj++) {
      const int n = nb + bj * 16 + l15;
      const float bn = bias[n];
      #pragma unroll
      for (int reg = 0; reg < 4; reg++) {
        const int m = mb + ai * 16 + g * 4 + reg;
        out[(size_t)m * Dc + n] = acc[ai][bj][reg] + bn;
      }
    }
}

// ---------------------------------------------------------------------------
// BF16 MFMA flash attention, double-buffered K/V with reg-prefetch (T14).
// Per tile: issue next-tile global loads -> compute current LDS tile ->
// write regs to the OTHER buffer -> ONE barrier.  Race-safe: each buffer's
// writes are separated from its last readers by the previous barrier.
// Math identical to the verified r4/r8/r10 kernel.
// ---------------------------------------------------------------------------
__global__ __launch_bounds__(256) void attn_mfma(
    const __hip_bfloat16* __restrict__ Q, const __hip_bfloat16* __restrict__ K,
    const __hip_bfloat16* __restrict__ Vt, float* __restrict__ ctx,
    __hip_bfloat16* __restrict__ ctxb) {
  __shared__ __hip_bfloat16 Ks0[64 * 64], Vs0[64 * 64];   // 16 KB
  __shared__ __hip_bfloat16 Ks1[64 * 64], Vs1[64 * 64];   // 16 KB

  const int tid = threadIdx.x;
  const int lane = tid & 63;
  const int w = tid >> 6;
  const int l15 = lane & 15;
  const int g = lane >> 4;

  const int cpx = gridDim.x >> 3;
  const int bid = blockIdx.x;
  const int wid = (bid & 7) * cpx + (bid >> 3);
  const int bh = wid >> 4;       // (b*H + h)
  const int qt = wid & 15;
  const int qbase = qt * 64 + w * 16;

  const __hip_bfloat16* Qb = Q + (size_t)bh * Sc * DKc;
  const __hip_bfloat16* Kb = K + (size_t)bh * Sc * DKc;
  const __hip_bfloat16* Vtb = Vt + (size_t)bh * DKc * Sc;  // [64][1024]

  short8 qf[2];
  {
    const __hip_bfloat16* qp = Qb + (size_t)(qbase + l15) * DKc + g * 8;
    qf[0] = *reinterpret_cast<const short8*>(qp);
    qf[1] = *reinterpret_cast<const short8*>(qp + 32);
  }

  f32x4 Oacc[4];
  #pragma unroll
  for (int dt = 0; dt < 4; dt++) Oacc[dt] = f32x4{0.f, 0.f, 0.f, 0.f};
  float m_run = -1e30f, l_run = 0.f;

  constexpr float SM_SCALE = 0.125f * 1.44269504088896340736f;

  float4 kr[2], vr[2];
  auto LOADT = [&](int kt) {
    #pragma unroll
    for (int it = 0; it < 2; it++) {
      const int tt = tid + it * 256;
      const int row = tt >> 3, s = tt & 7;
      kr[it] = *reinterpret_cast<const float4*>(
          Kb + (size_t)(kt + row) * DKc + s * 8);
      vr[it] = *reinterpret_cast<const float4*>(
          Vtb + (size_t)row * Sc + kt + s * 8);
    }
  };
  auto WRITET = [&](__hip_bfloat16* Kd, __hip_bfloat16* Vd) {
    #pragma unroll
    for (int it = 0; it < 2; it++) {
      const int tt = tid + it * 256;
      const int row = tt >> 3, s = tt & 7;
      const int off = row * 128 + ((s ^ (row & 7)) << 4);
      *reinterpret_cast<float4*>((char*)Kd + off) = kr[it];
      *reinterpret_cast<float4*>((char*)Vd + off) = vr[it];
    }
  };
  auto COMPUTE = [&](const __hip_bfloat16* Ksb, const __hip_bfloat16* Vsb) {
    f32x4 sacc[4];
    #pragma unroll
    for (int mt = 0; mt < 4; mt++) sacc[mt] = f32x4{0.f, 0.f, 0.f, 0.f};
    #pragma unroll
    for (int c = 0; c < 2; c++) {
      #pragma unroll
      for (int mt = 0; mt < 4; mt++) {
        const int row = mt * 16 + l15;
        const short8 kf = *reinterpret_cast<const short8*>(
            (const char*)Ksb + row * 128 + (((g + 4 * c) ^ (row & 7)) << 4));
        sacc[mt] =
            __builtin_amdgcn_mfma_f32_16x16x32_bf16(kf, qf[c], sacc[mt], 0, 0, 0);
      }
    }

    float tmax = -1e30f;
    #pragma unroll
    for (int s = 0; s < 4; s++)
      #pragma unroll
      for (int r = 0; r < 4; r++) tmax = fmaxf(tmax, sacc[s][r]);
    tmax = fmaxf(tmax, __shfl_xor(tmax, 16));
    tmax = fmaxf(tmax, __shfl_xor(tmax, 32));
    const float mnew = fmaxf(m_run, tmax);
    const float alpha = __builtin_amdgcn_exp2f((m_run - mnew) * SM_SCALE);
    m_run = mnew;
    float wgt[4][4];
    float wsum = 0.f;
    #pragma unroll
    for (int s = 0; s < 4; s++)
      #pragma unroll
      for (int r = 0; r < 4; r++) {
        wgt[s][r] = __builtin_amdgcn_exp2f((sacc[s][r] - mnew) * SM_SCALE);
        wsum += wgt[s][r];
      }
    l_run = l_run * alpha + wsum;

    float ar[4];
    #pragma unroll
    for (int r = 0; r < 4; r++) ar[r] = __shfl(alpha, g * 4 + r);
    #pragma unroll
    for (int dt = 0; dt < 4; dt++)
      #pragma unroll
      for (int r = 0; r < 4; r++) Oacc[dt][r] *= ar[r];

    short8 pa[2];
    #pragma unroll
    for (int c = 0; c < 2; c++)
      #pragma unroll
      for (int i = 0; i < 8; i++) pa[c][i] = f2bf(wgt[2 * c + (i >> 2)][i & 3]);

    #pragma unroll
    for (int dt = 0; dt < 4; dt++) {
      const int row = dt * 16 + l15;
      const int rb2 = row * 128;
      const int sw = row & 7;
      const int gl = (g & 1) * 8;
      const int gh = g >> 1;
      #pragma unroll
      for (int c = 0; c < 2; c++) {
        const short4v v0 = *reinterpret_cast<const short4v*>(
            (const char*)Vsb + rb2 + ((((4 * c + 0) + gh) ^ sw) << 4) + gl);
        const short4v v1 = *reinterpret_cast<const short4v*>(
            (const char*)Vsb + rb2 + ((((4 * c + 2) + gh) ^ sw) << 4) + gl);
        const short8 vf =
            __builtin_shufflevector(v0, v1, 0, 1, 2, 3, 4, 5, 6, 7);
        Oacc[dt] =
            __builtin_amdgcn_mfma_f32_16x16x32_bf16(pa[c], vf, Oacc[dt], 0, 0, 0);
      }
    }
  };

  // prologue: tile 0 -> buf0
  LOADT(0);
  WRITET(Ks0, Vs0);
  __syncthreads();

  // 16 tiles = 8 iterations x {buf0, buf1}
  #pragma unroll 1
  for (int j = 0; j < 8; j++) {
    LOADT(j * 128 + 64);          // tile 2j+1 (always exists)
    COMPUTE(Ks0, Vs0);            // tile 2j
    WRITET(Ks1, Vs1);
    __syncthreads();
    if (j < 7) LOADT(j * 128 + 128);  // tile 2j+2
    COMPUTE(Ks1, Vs1);            // tile 2j+1
    if (j < 7) {
      WRITET(Ks0, Vs0);
      __syncthreads();
    }
  }

  l_run += __shfl_xor(l_run, 16);
  l_run += __shfl_xor(l_run, 32);
  float linv[4];
  #pragma unroll
  for (int r = 0; r < 4; r++) linv[r] = 1.0f / __shfl(l_run, g * 4 + r);

  const int b_ = bh / Hc, h_ = bh % Hc;
  #pragma unroll
  for (int dt = 0; dt < 4; dt++)
    #pragma unroll
    for (int r = 0; r < 4; r++) {
      const int qa = qbase + g * 4 + r;
      const size_t idx =
          ((size_t)(b_ * Sc + qa)) * Dc + h_ * 64 + dt * 16 + l15;
      const float val = Oacc[dt][r] * linv[r];
      ctx[idx] = val;
      ctxb[idx] = __float2bfloat16(val);
    }
}

// ---------------------------------------------------------------------------
extern "C" void kernel_launch(void* const* d_in, const int* in_sizes, int n_in,
                              void* d_out, int out_size, void* d_ws,
                              size_t ws_size, hipStream_t stream) {
  const float* query = (const float*)d_in[0];
  const float* key_  = (const float*)d_in[1];
  const float* value = (const float*)d_in[2];
  const float* Wq = (const float*)d_in[3];
  const float* bq = (const float*)d_in[4];
  const float* Wk = (const float*)d_in[5];
  const float* bk = (const float*)d_in[6];
  const float* Wv = (const float*)d_in[7];
  const float* bv = (const float*)d_in[8];
  const float* Wd = (const float*)d_in[9];
  const float* bd = (const float*)d_in[10];

  float* out = (float*)d_out;
  float* hidden = out;                 // [B,S,D] fp32 (written LAST)
  float* context = out + OUT_ELEMS;    // [B,S,D] fp32

  // Scratch: Aq/Ak (bf16) live in the hidden region until gemm_qkv is done;
  // hidden is only written by the final gemm_o64.
  __hip_bfloat16* Aq = (__hip_bfloat16*)hidden;            // 12.6 MB
  __hip_bfloat16* Ak = Aq + OUT_ELEMS;                     // 12.6 MB

  __hip_bfloat16* Qw  = (__hip_bfloat16*)d_ws;       // [B,H,S,DK]
  __hip_bfloat16* Kw  = Qw + HEAD_ELEMS;             // [B,H,S,DK]
  __hip_bfloat16* Vtw = Kw + HEAD_ELEMS;             // [B,H,DK,S]
  __hip_bfloat16* WtQ = Vtw + HEAD_ELEMS;            // [4][768][768]
  __hip_bfloat16* WtD = WtQ + 3 * (size_t)Dc * Dc;
  __hip_bfloat16* Av  = WtQ + 4 * (size_t)Dc * Dc;   // 12.6 MB
  __hip_bfloat16* ctxb = Av;   // alias: Av dead after gemm_qkv; attn writes it
  // ws total: 37.75 + 4.5 + 12.6 = 54.9 MB  (<= 75.5 MB known-good)

  wtrans4<<<dim3(Dc / 32, Dc / 32, 4), 256, 0, stream>>>(Wq, Wk, Wv, Wd, WtQ);
  cast3<<<dim3(OUT_ELEMS / 8 / 256, 3), 256, 0, stream>>>(
      query, key_, value, Aq, Ak, Av);

  gemm_qkv<<<dim3((BSc / 128) * (Dc / 128), 3), 256, 0, stream>>>(
      Aq, Ak, Av, WtQ, bq, bk, bv, Qw);

  attn_mfma<<<Bc * Hc * (Sc / 64), 256, 0, stream>>>(Qw, Kw, Vtw, context,
                                                     ctxb);

  gemm_o64<<<(BSc / 64) * (Dc / 128), 256, 0, stream>>>(ctxb, WtD, bd, hidden);
}

// Round 13
// 267.961 us; speedup vs baseline: 1.1604x; 1.1604x over previous
//
#include <hip/hip_runtime.h>
#include <hip/hip_bf16.h>
#include <math.h>

// Problem constants
constexpr int Bc = 8;
constexpr int Sc = 1024;
constexpr int Dc = 768;
constexpr int Hc = 12;
constexpr int DKc = 64;
constexpr int BSc = Bc * Sc;          // 8192 rows
constexpr size_t HEAD_ELEMS = (size_t)Bc * Hc * Sc * DKc;  // 6291456
constexpr size_t OUT_ELEMS  = (size_t)Bc * Sc * Dc;        // 6291456

typedef __attribute__((ext_vector_type(8))) short short8;
typedef __attribute__((ext_vector_type(4))) short short4v;
typedef __attribute__((ext_vector_type(4))) float f32x4;

__device__ __forceinline__ short f2bf(float x) {
  __hip_bfloat16 h = __float2bfloat16(x);
  short r;
  __builtin_memcpy(&r, &h, 2);
  return r;
}

// async global->LDS, 16B per lane. LDS dest = wave-uniform base + lane*16.
__device__ __forceinline__ void gload16(const void* g, void* l) {
  __builtin_amdgcn_global_load_lds(
      (const __attribute__((address_space(1))) void*)g,
      (__attribute__((address_space(3))) void*)l, 16, 0, 0);
}

// ---------------------------------------------------------------------------
// Input cast: fp32 -> bf16, one short8 per thread.  Grid (3072, 3).
// ---------------------------------------------------------------------------
__global__ __launch_bounds__(256) void cast3(
    const float* __restrict__ q, const float* __restrict__ k,
    const float* __restrict__ v, __hip_bfloat16* __restrict__ dq,
    __hip_bfloat16* __restrict__ dk, __hip_bfloat16* __restrict__ dv) {
  const int which = blockIdx.y;
  const float* src = (which == 0) ? q : (which == 1) ? k : v;
  __hip_bfloat16* dst = (which == 0) ? dq : (which == 1) ? dk : dv;
  const size_t i = ((size_t)blockIdx.x * 256 + threadIdx.x) * 8;
  const float4 f0 = *reinterpret_cast<const float4*>(src + i);
  const float4 f1 = *reinterpret_cast<const float4*>(src + i + 4);
  short8 s;
  s[0] = f2bf(f0.x); s[1] = f2bf(f0.y); s[2] = f2bf(f0.z); s[3] = f2bf(f0.w);
  s[4] = f2bf(f1.x); s[5] = f2bf(f1.y); s[6] = f2bf(f1.z); s[7] = f2bf(f1.w);
  *reinterpret_cast<short8*>(dst + i) = s;
}

// ---------------------------------------------------------------------------
// Fused weight transpose+cast: Wt[z][n][k] bf16 = W_z[k][n] fp32.
// Grid (24,24,4), 256 threads.
// ---------------------------------------------------------------------------
__global__ __launch_bounds__(256) void wtrans4(
    const float* __restrict__ W0, const float* __restrict__ W1,
    const float* __restrict__ W2, const float* __restrict__ W3,
    __hip_bfloat16* __restrict__ Wt0) {
  __shared__ float t[32][33];
  const int z = blockIdx.z;
  const float* W = (z == 0) ? W0 : (z == 1) ? W1 : (z == 2) ? W2 : W3;
  __hip_bfloat16* Wt = Wt0 + (size_t)z * Dc * Dc;
  const int tx = threadIdx.x & 31, ty = threadIdx.x >> 5;
  const int bx = blockIdx.x * 32;   // n-base
  const int by = blockIdx.y * 32;   // k-base
  #pragma unroll
  for (int i = 0; i < 32; i += 8)
    t[ty + i][tx] = W[(size_t)(by + ty + i) * Dc + bx + tx];
  __syncthreads();
  #pragma unroll
  for (int i = 0; i < 32; i += 8)
    Wt[(size_t)(bx + ty + i) * Dc + by + tx] = __float2bfloat16(t[tx][ty + i]);
}

// ---------------------------------------------------------------------------
// Pipelined 2-phase BF16 GEMM core (128x128 tile, BK=32) -- verified r11.
// ---------------------------------------------------------------------------
__device__ __forceinline__ void stage_tiles(
    const __hip_bfloat16* A, const __hip_bfloat16* Wt, int row0, int col0,
    int k0, int wv, int lane, __hip_bfloat16* bufA, __hip_bfloat16* bufB) {
  #pragma unroll
  for (int j = 0; j < 2; j++) {
    const int rr = j * 64 + wv * 16;
    const int r = rr + (lane >> 2);
    const int kc = k0 + (lane & 3) * 8;
    gload16(A + (size_t)(row0 + r) * Dc + kc, bufA + rr * 32);
    gload16(Wt + (size_t)(col0 + r) * Dc + kc, bufB + rr * 32);
  }
}

__device__ __forceinline__ void compute_tiles(
    const __hip_bfloat16* bufA, const __hip_bfloat16* bufB, int wr, int wc,
    int l15, int g, f32x4 (&acc)[4][4]) {
  short8 a[4], b[4];
  #pragma unroll
  for (int ai = 0; ai < 4; ai++)
    a[ai] = *reinterpret_cast<const short8*>(
        &bufA[(wr * 64 + ai * 16 + l15) * 32 + g * 8]);
  #pragma unroll
  for (int bj = 0; bj < 4; bj++)
    b[bj] = *reinterpret_cast<const short8*>(
        &bufB[(wc * 64 + bj * 16 + l15) * 32 + g * 8]);
  #pragma unroll
  for (int ai = 0; ai < 4; ai++)
    #pragma unroll
    for (int bj = 0; bj < 4; bj++)
      acc[ai][bj] = __builtin_amdgcn_mfma_f32_16x16x32_bf16(
          a[ai], b[bj], acc[ai][bj], 0, 0, 0);
}

#define GEMM_PIPELINE(A_, Wt_)                                          \
  stage_tiles(A_, Wt_, row0, col0, 0, wv, lane, As0, Bs0);              \
  __syncthreads();                                                      \
  for (int t = 0; t < 24; t += 2) {                                     \
    stage_tiles(A_, Wt_, row0, col0, (t + 1) * 32, wv, lane, As1, Bs1); \
    compute_tiles(As0, Bs0, wr, wc, l15, g, acc);                       \
    __syncthreads();                                                    \
    if (t + 2 < 24)                                                     \
      stage_tiles(A_, Wt_, row0, col0, (t + 2) * 32, wv, lane, As0, Bs0);\
    compute_tiles(As1, Bs1, wr, wc, l15, g, acc);                       \
    __syncthreads();                                                    \
  }

// ---------------------------------------------------------------------------
// Fused QKV GEMM (verified r11).  Grid (384, 3).
// ---------------------------------------------------------------------------
__global__ __launch_bounds__(256) void gemm_qkv(
    const __hip_bfloat16* __restrict__ Aq, const __hip_bfloat16* __restrict__ Ak,
    const __hip_bfloat16* __restrict__ Av, const __hip_bfloat16* __restrict__ Wt0,
    const float* __restrict__ bq, const float* __restrict__ bk,
    const float* __restrict__ bv, __hip_bfloat16* __restrict__ out0) {
  __shared__ __hip_bfloat16 As0[128 * 32], Bs0[128 * 32];
  __shared__ __hip_bfloat16 As1[128 * 32], Bs1[128 * 32];

  const int tid = threadIdx.x;
  const int lane = tid & 63;
  const int wv = tid >> 6;
  const int l15 = lane & 15;
  const int g = lane >> 4;
  const int wr = wv >> 1, wc = wv & 1;

  const int proj = blockIdx.y;
  const __hip_bfloat16* A = (proj == 0) ? Aq : (proj == 1) ? Ak : Av;
  const float* bias = (proj == 0) ? bq : (proj == 1) ? bk : bv;
  const __hip_bfloat16* Wt = Wt0 + (size_t)proj * Dc * Dc;
  __hip_bfloat16* out = out0 + (size_t)proj * HEAD_ELEMS;

  const int orig = blockIdx.x;
  const int swz = (orig & 7) * 48 + (orig >> 3);
  const int row0 = (swz / (Dc / 128)) * 128;
  const int col0 = (swz % (Dc / 128)) * 128;

  f32x4 acc[4][4];
  #pragma unroll
  for (int ai = 0; ai < 4; ai++)
    #pragma unroll
    for (int bj = 0; bj < 4; bj++) acc[ai][bj] = f32x4{0.f, 0.f, 0.f, 0.f};

  GEMM_PIPELINE(A, Wt)

  const int mb = row0 + wr * 64, nb = col0 + wc * 64;
  if (proj < 2) {
    #pragma unroll
    for (int ai = 0; ai < 4; ai++)
      #pragma unroll
      for (int bj = 0; bj < 4; bj++) {
        const int n = nb + bj * 16 + l15;
        const int h_ = n >> 6, dk = n & 63;
        const float bn = bias[n];
        #pragma unroll
        for (int reg = 0; reg < 4; reg++) {
          const int m = mb + ai * 16 + g * 4 + reg;
          const int b_ = m >> 10, s_ = m & 1023;
          out[(((size_t)(b_ * Hc + h_)) * Sc + s_) * DKc + dk] =
              __float2bfloat16(acc[ai][bj][reg] + bn);
        }
      }
  } else {
    #pragma unroll
    for (int ai = 0; ai < 4; ai++)
      #pragma unroll
      for (int bj = 0; bj < 4; bj++) {
        const int n = nb + bj * 16 + l15;          // d index
        const int h_ = n >> 6, dk = n & 63;
        const float bn = bias[n];
        const int m0 = mb + ai * 16 + g * 4;       // s base (mult of 4)
        const int b_ = m0 >> 10, s0 = m0 & 1023;
        short4v sv;
        sv[0] = f2bf(acc[ai][bj][0] + bn);
        sv[1] = f2bf(acc[ai][bj][1] + bn);
        sv[2] = f2bf(acc[ai][bj][2] + bn);
        sv[3] = f2bf(acc[ai][bj][3] + bn);
        *reinterpret_cast<short4v*>(
            &out[(((size_t)(b_ * Hc + h_)) * DKc + dk) * Sc + s0]) = sv;
      }
  }
}

// ---------------------------------------------------------------------------
// Output projection, 64x128 tiles -> 768 blocks (kept from r12, neutral).
// hidden[8192,768] fp32 = ctx_bf @ WtD^T + bd.  4 waves 2x2: 32x64/wave.
// ---------------------------------------------------------------------------
__global__ __launch_bounds__(256) void gemm_o64(
    const __hip_bfloat16* __restrict__ A, const __hip_bfloat16* __restrict__ Wt,
    const float* __restrict__ bias, float* __restrict__ out) {
  __shared__ __hip_bfloat16 As0[64 * 32], As1[64 * 32];    // 4 KB each
  __shared__ __hip_bfloat16 Bs0[128 * 32], Bs1[128 * 32];  // 8 KB each

  const int tid = threadIdx.x;
  const int lane = tid & 63;
  const int wv = tid >> 6;
  const int l15 = lane & 15;
  const int g = lane >> 4;
  const int wr = wv >> 1, wc = wv & 1;

  // XCD swizzle; nwg = 768, divisible by 8 -> bijective
  const int orig = blockIdx.x;
  const int swz = (orig & 7) * 96 + (orig >> 3);
  const int row0 = (swz / (Dc / 128)) * 64;
  const int col0 = (swz % (Dc / 128)) * 128;

  f32x4 acc[2][4];
  #pragma unroll
  for (int ai = 0; ai < 2; ai++)
    #pragma unroll
    for (int bj = 0; bj < 4; bj++) acc[ai][bj] = f32x4{0.f, 0.f, 0.f, 0.f};

  auto STAGE = [&](int k0, __hip_bfloat16* bufA, __hip_bfloat16* bufB) {
    const int r = wv * 16 + (lane >> 2);
    const int kc = k0 + (lane & 3) * 8;
    gload16(A + (size_t)(row0 + r) * Dc + kc, bufA + (wv * 16) * 32);
    #pragma unroll
    for (int j = 0; j < 2; j++) {
      const int rr = j * 64 + wv * 16;
      const int rn = rr + (lane >> 2);
      gload16(Wt + (size_t)(col0 + rn) * Dc + kc, bufB + rr * 32);
    }
  };
  auto COMP = [&](const __hip_bfloat16* bufA, const __hip_bfloat16* bufB) {
    short8 a[2], b[4];
    #pragma unroll
    for (int ai = 0; ai < 2; ai++)
      a[ai] = *reinterpret_cast<const short8*>(
          &bufA[(wr * 32 + ai * 16 + l15) * 32 + g * 8]);
    #pragma unroll
    for (int bj = 0; bj < 4; bj++)
      b[bj] = *reinterpret_cast<const short8*>(
          &bufB[(wc * 64 + bj * 16 + l15) * 32 + g * 8]);
    #pragma unroll
    for (int ai = 0; ai < 2; ai++)
      #pragma unroll
      for (int bj = 0; bj < 4; bj++)
        acc[ai][bj] = __builtin_amdgcn_mfma_f32_16x16x32_bf16(
            a[ai], b[bj], acc[ai][bj], 0, 0, 0);
  };

  STAGE(0, As0, Bs0);
  __syncthreads();
  for (int t = 0; t < 24; t += 2) {
    STAGE((t + 1) * 32, As1, Bs1);
    COMP(As0, Bs0);
    __syncthreads();
    if (t + 2 < 24) STAGE((t + 2) * 32, As0, Bs0);
    COMP(As1, Bs1);
    __syncthreads();
  }

  const int mb = row0 + wr * 32, nb = col0 + wc * 64;
  #pragma unroll
  for (int ai = 0; ai < 2; ai++)
    #pragma unroll
    for (int bj = 0; bj < 4; bj++) {
      const int n = nb + bj * 16 + l15;
      const float bn = bias[n];
      #pragma unroll
      for (int reg = 0; reg < 4; reg++) {
        const int m = mb + ai * 16 + g * 4 + reg;
        out[(size_t)m * Dc + n] = acc[ai][bj][reg] + bn;
      }
    }
}

// ---------------------------------------------------------------------------
// BF16 MFMA flash attention, double-buffered K/V via global_load_lds with
// PRE-SWIZZLED GLOBAL SOURCE (rule #21 / m201 stage_rc pattern):
// LDS dest linear (HW requires wave-base + lane*16); the lane serving LDS
// chunk (row, sl) fetches global chunk s_src = sl ^ (row&7), so LDS content
// equals the verified swizzled layout bit-for-bit; read side unchanged.
// 2-phase schedule as in the r11 GEMM: stage(t+1) issued before compute(t);
// barrier drains vmcnt. No registers held across compute -> no spill (r12
// regression mechanism eliminated).  Math identical to verified r4/r8/r10.
// ---------------------------------------------------------------------------
__global__ __launch_bounds__(256) void attn_mfma(
    const __hip_bfloat16* __restrict__ Q, const __hip_bfloat16* __restrict__ K,
    const __hip_bfloat16* __restrict__ Vt, float* __restrict__ ctx,
    __hip_bfloat16* __restrict__ ctxb) {
  __shared__ __hip_bfloat16 Ks0[64 * 64], Vs0[64 * 64];   // 16 KB
  __shared__ __hip_bfloat16 Ks1[64 * 64], Vs1[64 * 64];   // 16 KB

  const int tid = threadIdx.x;
  const int lane = tid & 63;
  const int w = tid >> 6;
  const int l15 = lane & 15;
  const int g = lane >> 4;

  const int cpx = gridDim.x >> 3;
  const int bid = blockIdx.x;
  const int wid = (bid & 7) * cpx + (bid >> 3);
  const int bh = wid >> 4;       // (b*H + h)
  const int qt = wid & 15;
  const int qbase = qt * 64 + w * 16;

  const __hip_bfloat16* Qb = Q + (size_t)bh * Sc * DKc;
  const __hip_bfloat16* Kb = K + (size_t)bh * Sc * DKc;
  const __hip_bfloat16* Vtb = Vt + (size_t)bh * DKc * Sc;  // [64][1024]

  short8 qf[2];
  {
    const __hip_bfloat16* qp = Qb + (size_t)(qbase + l15) * DKc + g * 8;
    qf[0] = *reinterpret_cast<const short8*>(qp);
    qf[1] = *reinterpret_cast<const short8*>(qp + 32);
  }

  f32x4 Oacc[4];
  #pragma unroll
  for (int dt = 0; dt < 4; dt++) Oacc[dt] = f32x4{0.f, 0.f, 0.f, 0.f};
  float m_run = -1e30f, l_run = 0.f;

  constexpr float SM_SCALE = 0.125f * 1.44269504088896340736f;

  // async stage one 64-row K/V tile into (Kd, Vd); 2 calls/wave, 1 KB each
  auto STAGE = [&](int kt, __hip_bfloat16* Kd, __hip_bfloat16* Vd) {
    #pragma unroll
    for (int j = 0; j < 2; j++) {
      const int cb = (w * 2 + j) * 64;        // wave-uniform chunk base
      const int c = cb + lane;                // this lane's LDS chunk
      const int row = c >> 3;
      const int s_src = (c & 7) ^ (row & 7);  // pre-swizzled source chunk
      gload16(Kb + (size_t)(kt + row) * DKc + s_src * 8, (char*)Kd + cb * 16);
      gload16(Vtb + (size_t)row * Sc + kt + s_src * 8, (char*)Vd + cb * 16);
    }
  };

  auto COMPUTE = [&](const __hip_bfloat16* Ksb, const __hip_bfloat16* Vsb) {
    f32x4 sacc[4];
    #pragma unroll
    for (int mt = 0; mt < 4; mt++) sacc[mt] = f32x4{0.f, 0.f, 0.f, 0.f};
    #pragma unroll
    for (int c = 0; c < 2; c++) {
      #pragma unroll
      for (int mt = 0; mt < 4; mt++) {
        const int row = mt * 16 + l15;
        const short8 kf = *reinterpret_cast<const short8*>(
            (const char*)Ksb + row * 128 + (((g + 4 * c) ^ (row & 7)) << 4));
        sacc[mt] =
            __builtin_amdgcn_mfma_f32_16x16x32_bf16(kf, qf[c], sacc[mt], 0, 0, 0);
      }
    }

    float tmax = -1e30f;
    #pragma unroll
    for (int s = 0; s < 4; s++)
      #pragma unroll
      for (int r = 0; r < 4; r++) tmax = fmaxf(tmax, sacc[s][r]);
    tmax = fmaxf(tmax, __shfl_xor(tmax, 16));
    tmax = fmaxf(tmax, __shfl_xor(tmax, 32));
    const float mnew = fmaxf(m_run, tmax);
    const float alpha = __builtin_amdgcn_exp2f((m_run - mnew) * SM_SCALE);
    m_run = mnew;
    float wgt[4][4];
    float wsum = 0.f;
    #pragma unroll
    for (int s = 0; s < 4; s++)
      #pragma unroll
      for (int r = 0; r < 4; r++) {
        wgt[s][r] = __builtin_amdgcn_exp2f((sacc[s][r] - mnew) * SM_SCALE);
        wsum += wgt[s][r];
      }
    l_run = l_run * alpha + wsum;

    float ar[4];
    #pragma unroll
    for (int r = 0; r < 4; r++) ar[r] = __shfl(alpha, g * 4 + r);
    #pragma unroll
    for (int dt = 0; dt < 4; dt++)
      #pragma unroll
      for (int r = 0; r < 4; r++) Oacc[dt][r] *= ar[r];

    short8 pa[2];
    #pragma unroll
    for (int c = 0; c < 2; c++)
      #pragma unroll
      for (int i = 0; i < 8; i++) pa[c][i] = f2bf(wgt[2 * c + (i >> 2)][i & 3]);

    #pragma unroll
    for (int dt = 0; dt < 4; dt++) {
      const int row = dt * 16 + l15;
      const int rb2 = row * 128;
      const int sw = row & 7;
      const int gl = (g & 1) * 8;
      const int gh = g >> 1;
      #pragma unroll
      for (int c = 0; c < 2; c++) {
        const short4v v0 = *reinterpret_cast<const short4v*>(
            (const char*)Vsb + rb2 + ((((4 * c + 0) + gh) ^ sw) << 4) + gl);
        const short4v v1 = *reinterpret_cast<const short4v*>(
            (const char*)Vsb + rb2 + ((((4 * c + 2) + gh) ^ sw) << 4) + gl);
        const short8 vf =
            __builtin_shufflevector(v0, v1, 0, 1, 2, 3, 4, 5, 6, 7);
        Oacc[dt] =
            __builtin_amdgcn_mfma_f32_16x16x32_bf16(pa[c], vf, Oacc[dt], 0, 0, 0);
      }
    }
  };

  // prologue: tile 0 -> buf0
  STAGE(0, Ks0, Vs0);
  __syncthreads();

  // 16 tiles, 2 per iteration
  #pragma unroll 1
  for (int t = 0; t < 16; t += 2) {
    STAGE((t + 1) * 64, Ks1, Vs1);     // t+1 <= 15 always
    COMPUTE(Ks0, Vs0);
    __syncthreads();                   // drains buf1 loads; buf0 readers done
    if (t + 2 < 16) STAGE((t + 2) * 64, Ks0, Vs0);
    COMPUTE(Ks1, Vs1);
    __syncthreads();
  }

  l_run += __shfl_xor(l_run, 16);
  l_run += __shfl_xor(l_run, 32);
  float linv[4];
  #pragma unroll
  for (int r = 0; r < 4; r++) linv[r] = 1.0f / __shfl(l_run, g * 4 + r);

  const int b_ = bh / Hc, h_ = bh % Hc;
  #pragma unroll
  for (int dt = 0; dt < 4; dt++)
    #pragma unroll
    for (int r = 0; r < 4; r++) {
      const int qa = qbase + g * 4 + r;
      const size_t idx =
          ((size_t)(b_ * Sc + qa)) * Dc + h_ * 64 + dt * 16 + l15;
      const float val = Oacc[dt][r] * linv[r];
      ctx[idx] = val;
      ctxb[idx] = __float2bfloat16(val);
    }
}

// ---------------------------------------------------------------------------
extern "C" void kernel_launch(void* const* d_in, const int* in_sizes, int n_in,
                              void* d_out, int out_size, void* d_ws,
                              size_t ws_size, hipStream_t stream) {
  const float* query = (const float*)d_in[0];
  const float* key_  = (const float*)d_in[1];
  const float* value = (const float*)d_in[2];
  const float* Wq = (const float*)d_in[3];
  const float* bq = (const float*)d_in[4];
  const float* Wk = (const float*)d_in[5];
  const float* bk = (const float*)d_in[6];
  const float* Wv = (const float*)d_in[7];
  const float* bv = (const float*)d_in[8];
  const float* Wd = (const float*)d_in[9];
  const float* bd = (const float*)d_in[10];

  float* out = (float*)d_out;
  float* hidden = out;                 // [B,S,D] fp32 (written LAST)
  float* context = out + OUT_ELEMS;    // [B,S,D] fp32

  // Scratch: Aq/Ak (bf16) live in the hidden region until gemm_qkv is done;
  // hidden is only written by the final gemm_o64.
  __hip_bfloat16* Aq = (__hip_bfloat16*)hidden;            // 12.6 MB
  __hip_bfloat16* Ak = Aq + OUT_ELEMS;                     // 12.6 MB

  __hip_bfloat16* Qw  = (__hip_bfloat16*)d_ws;       // [B,H,S,DK]
  __hip_bfloat16* Kw  = Qw + HEAD_ELEMS;             // [B,H,S,DK]
  __hip_bfloat16* Vtw = Kw + HEAD_ELEMS;             // [B,H,DK,S]
  __hip_bfloat16* WtQ = Vtw + HEAD_ELEMS;            // [4][768][768]
  __hip_bfloat16* WtD = WtQ + 3 * (size_t)Dc * Dc;
  __hip_bfloat16* Av  = WtQ + 4 * (size_t)Dc * Dc;   // 12.6 MB
  __hip_bfloat16* ctxb = Av;   // alias: Av dead after gemm_qkv; attn writes it
  // ws total: 37.75 + 4.5 + 12.6 = 54.9 MB  (<= 75.5 MB known-good)

  wtrans4<<<dim3(Dc / 32, Dc / 32, 4), 256, 0, stream>>>(Wq, Wk, Wv, Wd, WtQ);
  cast3<<<dim3(OUT_ELEMS / 8 / 256, 3), 256, 0, stream>>>(
      query, key_, value, Aq, Ak, Av);

  gemm_qkv<<<dim3((BSc / 128) * (Dc / 128), 3), 256, 0, stream>>>(
      Aq, Ak, Av, WtQ, bq, bk, bv, Qw);

  attn_mfma<<<Bc * Hc * (Sc / 64), 256, 0, stream>>>(Qw, Kw, Vtw, context,
                                                     ctxb);

  gemm_o64<<<(BSc / 64) * (Dc / 128), 256, 0, stream>>>(ctxb, WtD, bd, hidden);
}